// Round 9
// baseline (375.830 us; speedup 1.0000x reference)
//
#include <hip/hip_runtime.h>
#include <cstdint>
#include <math.h>

// Problem constants
#define Bsz 4
#define Lsz 1024
#define Dsz 256
#define Hsz 8
#define HD  2048          // H*D
#define NROWS (Bsz*Lsz)   // 4096
#define INV_TEMP 0.0625f  // 1/sqrt(256)

typedef __attribute__((ext_vector_type(8))) short bf16x8;
typedef __attribute__((ext_vector_type(4))) float f32x4;

__device__ inline unsigned short f2bf(float f) {
    union { float f; unsigned u; } x; x.f = f;
    unsigned r = x.u + 0x7fffu + ((x.u >> 16) & 1u);
    return (unsigned short)(r >> 16);
}
__device__ inline float bf2f(unsigned short u) {
    union { unsigned u; float f; } x; x.u = (unsigned)u << 16; return x.f;
}

#define GBL(p) ((const __attribute__((address_space(1))) unsigned int*)(p))
#define LDS(p) ((__attribute__((address_space(3))) unsigned int*)(p))

template<int N> __device__ __forceinline__ void vmw() {
    if constexpr (N == 0)       asm volatile("s_waitcnt vmcnt(0)"  ::: "memory");
    else if constexpr (N == 4)  asm volatile("s_waitcnt vmcnt(4)"  ::: "memory");
    else if constexpr (N == 6)  asm volatile("s_waitcnt vmcnt(6)"  ::: "memory");
    else if constexpr (N == 10) asm volatile("s_waitcnt vmcnt(10)" ::: "memory");
    else if constexpr (N == 14) asm volatile("s_waitcnt vmcnt(14)" ::: "memory");
    else static_assert(N == 0, "unsupported vmcnt literal");
}

// C = alpha * A @ B^T.  A [M,K] bf16 lda; Bm [N,K] bf16 ldb.
// BK=64, XOR-swizzled LDS staging + ds_read_b128 frags; counted-vmcnt dbuf pipeline.
// 4 waves as 2x2 quadrants of (TMv/2)x(TNv/2).  XCD-aware bijective wg remap (T1).
//
// Round 9 (= round 8 with compile fix): NONTEMPORAL stores on every write-once
// stream never re-read within the producing dispatch (e bf16, attn fp32, fcout
// fp32) and NT loads on read-once mask bytes. Round-2 pv counters showed
// FETCH=131 MB vs ~67 MB dedup'd ideal -- reused vt/e panels were evicted by
// the 128 MB attn write-allocate stream. NT keeps streams out of L2.
// Fix vs round 8: __builtin_nontemporal_store requires true vector types ->
// use ext_vector f32x4, not HIP_vector_type float4.
//
// EPI: 0 = plain store (float path = fc partials -> NT)
//      1 = scores: clamp*mask, exp*mask, bf16 NT store; mask bytes NT-loaded;
//          per-row partial sums atomicAdd'd into aux[z*Lsz+row] (bf16-ROUNDED).
//      2 = pv (TNv=256, gridDim.y==1): scale attnv by inv=1/(rowsum+eps);
//          IN-LOOP: re-read A(e)-tile from LDS, normalize, NT-write fp32 attn.
// FUSE: z<2 = q/k projection; z in [2,6) = vt[b=z-2] = w_vs @ v_b^T remapped.
template <int TMv, int TNv, typename OutT, int EPI, int MINW, bool FUSE,
          int GX, int GY, int GZ>
__global__ __launch_bounds__(256, MINW) void gemm_bt(
    const unsigned short* __restrict__ A, const unsigned short* __restrict__ Bm,
    OutT* __restrict__ C,
    int K, int lda, int ldb, int ldc, int inner,
    long long sA1, long long sA2, long long sB1, long long sB2,
    long long sC1, long long sC2, float alpha,
    const unsigned char* __restrict__ maskb, long long sM2,
    const float* __restrict__ invs, long long sI1, long long sI2,
    float* __restrict__ aux,
    const unsigned short* __restrict__ A2, const unsigned short* __restrict__ B2,
    unsigned short* __restrict__ C2)
{
    constexpr int WMv = TMv / 2, WNv = TNv / 2;
    constexpr int IT = TMv / 32, JT = TNv / 32;
    constexpr int APASS = TMv / 32, NPASS = (TMv + TNv) / 32;
    constexpr int TILE = (TMv + TNv) * 64;   // ushorts per k-tile
    constexpr int G = GX * GY * GZ;
    static_assert(G % 8 == 0, "bijective XCD swizzle needs G%8==0");
    static_assert(NPASS == 6 || NPASS == 10, "vmcnt literals assume NPASS in {6,10}");

    // ---- XCD-aware bijective remap: each XCD gets a contiguous nid chunk ----
    const int lid = blockIdx.x + GX * (blockIdx.y + GY * blockIdx.z);
    const int nid = (lid & 7) * (G >> 3) + (lid >> 3);
    int mx = nid % GX;
    const int t1g = nid / GX;
    int my = t1g % GY;
    const int z  = t1g / GY;

    if constexpr (FUSE) {
        if (z >= 2) {
            const int idx = my * 64 + mx;
            if (idx >= 256) return;            // vt slice is 32x8 wg-tiles
            mx = idx & 31; my = idx >> 5;
            const int b = z - 2;
            A   = A2;
            Bm  = B2 + (size_t)b * ((size_t)Lsz * Dsz);
            C   = (OutT*)(C2 + (size_t)b * ((size_t)HD * Lsz));
            ldc = Lsz;
        } else {
            A  += (size_t)z * sA2;
            Bm += (size_t)z * sB2;
            C  += (size_t)z * sC2;
        }
    } else {
        const int i1 = z / inner;
        const int i2 = z % inner;
        A  += (size_t)i1 * sA1 + (size_t)i2 * sA2;
        Bm += (size_t)i1 * sB1 + (size_t)i2 * sB2;
        C  += (size_t)i1 * sC1 + (size_t)i2 * sC2;
        if (EPI == 1) { maskb += (size_t)i2 * sM2; aux += (size_t)z * Lsz; }
        if (EPI == 2) { invs  += (size_t)i1 * sI1 + (size_t)i2 * sI2; aux += (size_t)z * Lsz * Lsz; }
    }

    __shared__ unsigned short S[2 * TILE];

    const int t    = threadIdx.x;
    const int lane = t & 63;
    const int w    = t >> 6;
    const int wm   = w & 1;
    const int wn   = w >> 1;
    const int m0   = mx * TMv;
    const int n0   = my * TNv;

    // staging: 32 rows per pass, 8 threads/row, 16B each; global chunk XOR-swizzled by row
    const int rA = t >> 3;
    const int ch = ((t & 7) ^ (rA & 7)) * 8;
    const unsigned short* gA = A  + (size_t)(m0 + rA) * lda + ch;
    const unsigned short* gB = Bm + (size_t)(n0 + rA) * ldb + ch;

    const int fr = lane & 15;
    const int q  = lane >> 4;

    f32x4 acc[IT][JT];
#pragma unroll
    for (int i = 0; i < IT; ++i)
#pragma unroll
        for (int j = 0; j < JT; ++j) acc[i][j] = (f32x4){0.f, 0.f, 0.f, 0.f};

    auto stage = [&](unsigned short* Sb, int k0) {
#pragma unroll
        for (int p = 0; p < NPASS; ++p) {
            const unsigned short* src = (p < APASS)
                ? (gA + (size_t)p * 32 * lda + k0)
                : (gB + (size_t)(p - APASS) * 32 * ldb + k0);
            __builtin_amdgcn_global_load_lds(GBL(src), LDS(Sb + p * 2048 + t * 8), 16, 0, 0);
        }
    };
    auto kstep = [&](const unsigned short* As) {
        const unsigned short* Bs = As + TMv * 64;
#pragma unroll
        for (int ks = 0; ks < 2; ++ks) {
            const int slot = ((ks * 4 + q) ^ (fr & 7)) * 8;  // de-swizzle
            bf16x8 a[IT], b[JT];
#pragma unroll
            for (int i = 0; i < IT; ++i)
                a[i] = *(const bf16x8*)(As + (wm * WMv + i * 16 + fr) * 64 + slot);
#pragma unroll
            for (int j = 0; j < JT; ++j)
                b[j] = *(const bf16x8*)(Bs + (wn * WNv + j * 16 + fr) * 64 + slot);
#pragma unroll
            for (int i = 0; i < IT; ++i)
#pragma unroll
                for (int j = 0; j < JT; ++j)
                    acc[i][j] = __builtin_amdgcn_mfma_f32_16x16x32_bf16(a[i], b[j], acc[i][j], 0, 0, 0);
        }
    };

    const int nk = K >> 6;

    // EPI==2: per-thread inv for the 2 attn-write rows (regs); drain the loads
    // BEFORE staging so counted in-loop waits see only tile loads + attn stores.
    float ainv[EPI == 2 ? (TMv / 32) : 1];
    if constexpr (EPI == 2) {
        const int rsub = lane >> 3;
#pragma unroll
        for (int pass = 0; pass < TMv / 32; ++pass)
            ainv[pass] = 1.0f / (invs[m0 + w * (TMv / 4) + pass * 8 + rsub] + 1e-6f);
        vmw<0>();
    }

    stage(S, 0);

    for (int kt = 0; kt < nk; ++kt) {
        if (kt + 1 < nk) stage(S + ((kt + 1) & 1) * TILE, (kt + 1) << 6);

        // wait only for tile kt's loads (oldest-first retirement, m135);
        // EPI==2 adds +4 slack for the previous iteration's 4 attn stores.
        if constexpr (EPI == 2) {
            if (kt + 1 < nk) { if (kt >= 1) vmw<NPASS + 4>(); else vmw<NPASS>(); }
            else             { if (kt >= 1) vmw<4>();         else vmw<0>(); }
        } else {
            if (kt + 1 < nk) vmw<NPASS>(); else vmw<0>();
        }
        __builtin_amdgcn_s_barrier();

        kstep(S + (kt & 1) * TILE);

        if constexpr (EPI == 2) {
            // normalized fp32 attn NT-write for this k-tile's A(e) rows, from LDS (every kt)
            const unsigned short* As = S + (kt & 1) * TILE;
            const int chunk = lane & 7;
            const int rsub  = lane >> 3;
#pragma unroll
            for (int pass = 0; pass < TMv / 32; ++pass) {
                const int row = w * (TMv / 4) + pass * 8 + rsub;
                const uint4 u = *(const uint4*)(As + row * 64 + ((chunk ^ (row & 7)) * 8));
                const float iv = ainv[pass];
                f32x4 lo, hi;
                lo.x = bf2f((unsigned short)(u.x & 0xffff)) * iv; lo.y = bf2f((unsigned short)(u.x >> 16)) * iv;
                lo.z = bf2f((unsigned short)(u.y & 0xffff)) * iv; lo.w = bf2f((unsigned short)(u.y >> 16)) * iv;
                hi.x = bf2f((unsigned short)(u.z & 0xffff)) * iv; hi.y = bf2f((unsigned short)(u.z >> 16)) * iv;
                hi.z = bf2f((unsigned short)(u.w & 0xffff)) * iv; hi.w = bf2f((unsigned short)(u.w >> 16)) * iv;
                float* op = aux + (size_t)(m0 + row) * Lsz + (kt << 6) + chunk * 8;
                __builtin_nontemporal_store(lo, (f32x4*)op);
                __builtin_nontemporal_store(hi, (f32x4*)(op + 4));
            }
        }

        // readers done with buf[kt] before iter kt+1 overwrites it; do NOT drain vmcnt
        asm volatile("s_waitcnt lgkmcnt(0)" ::: "memory");
        __builtin_amdgcn_s_barrier();
    }

    // EPI==2: per-accumulator-row inv (8 rows/thread), L2-hot scalar loads
    float einv[EPI == 2 ? IT : 1][EPI == 2 ? 4 : 1];
    if constexpr (EPI == 2) {
#pragma unroll
        for (int i = 0; i < IT; ++i)
#pragma unroll
            for (int r = 0; r < 4; ++r)
                einv[i][r] = 1.0f / (invs[m0 + wm * WMv + i * 16 + q * 4 + r] + 1e-6f);
    }

    // epilogue: C/D layout col = lane&15, row = (lane>>4)*4 + reg
#pragma unroll
    for (int i = 0; i < IT; ++i) {
#pragma unroll
        for (int r = 0; r < 4; ++r) {
            const int row = m0 + wm * WMv + i * 16 + q * 4 + r;
            float rsum = 0.f;
#pragma unroll
            for (int j = 0; j < JT; ++j) {
                const int col = n0 + wn * WNv + j * 16 + fr;
                float vv = acc[i][j][r] * alpha;
                if (EPI == 0) {
                    if constexpr (sizeof(OutT) == 4)
                        __builtin_nontemporal_store((float)vv, (float*)&C[(size_t)row * ldc + col]);
                    else
                        ((unsigned short*)C)[(size_t)row * ldc + col] = f2bf(vv);
                } else if (EPI == 1) {
                    const float m = (float)__builtin_nontemporal_load(&maskb[(size_t)row * Lsz + col]);
                    vv = fminf(fmaxf(vv, -15.f), 15.f) * m;
                    vv = __expf(vv) * m;
                    const unsigned short us = f2bf(vv);
                    __builtin_nontemporal_store(us, &((unsigned short*)C)[(size_t)row * ldc + col]);
                    rsum += bf2f(us);   // sum the ROUNDED value
                } else {
                    vv *= einv[i][r];
                    ((unsigned short*)C)[(size_t)row * ldc + col] = f2bf(vv);
                }
            }
            if constexpr (EPI == 1) {
                // reduce over the 16 fr-lanes of this q-group -> 64-col partial sum
#pragma unroll
                for (int o = 1; o <= 8; o <<= 1) rsum += __shfl_xor(rsum, o, 64);
                if (fr == 0) atomicAdd(&aux[row], rsum);
            }
        }
    }
}

// ---- fp32->bf16 cast of all GEMM inputs + int32 mask -> BYTE {0,1} + rowsum zero ----
__global__ __launch_bounds__(256) void cast_all(
    const float* __restrict__ q, const float* __restrict__ k, const float* __restrict__ v,
    const float* __restrict__ wq, const float* __restrict__ wk, const float* __restrict__ wv,
    const float* __restrict__ fw, const int* __restrict__ mask,
    unsigned short* __restrict__ qb, unsigned short* __restrict__ kb, unsigned short* __restrict__ vb,
    unsigned short* __restrict__ wqb, unsigned short* __restrict__ wkb, unsigned short* __restrict__ wvb,
    unsigned short* __restrict__ fwb, unsigned char* __restrict__ mb,
    float* __restrict__ rs)
{
    const int gid = blockIdx.x * 256 + threadIdx.x;
    const int NQ = 262144;   // 1048576/4
    const int NW = 131072;   // 524288/4
    const int NF = 3 * NQ + 4 * NW;   // 1310720 float4 groups
    const int NM = 1048576;           // mask int4 groups
    if (gid >= NF) {
        const int off = gid - NF;
        if (off >= NM) {
            const int ri = off - NM;
            if (ri < 8192) ((float4*)rs)[ri] = (float4){0.f, 0.f, 0.f, 0.f};
            return;
        }
        const int4 mi = ((const int4*)mask)[off];
        uchar4 o;
        o.x = mi.x ? 1 : 0;
        o.y = mi.y ? 1 : 0;
        o.z = mi.z ? 1 : 0;
        o.w = mi.w ? 1 : 0;
        ((uchar4*)mb)[off] = o;
        return;
    }
    const float* src; unsigned short* dst; int off;
    if      (gid < NQ)            { src = q;  dst = qb;  off = gid; }
    else if (gid < 2 * NQ)        { src = k;  dst = kb;  off = gid - NQ; }
    else if (gid < 3 * NQ)        { src = v;  dst = vb;  off = gid - 2 * NQ; }
    else if (gid < 3 * NQ + NW)   { src = wq; dst = wqb; off = gid - 3 * NQ; }
    else if (gid < 3 * NQ + 2*NW) { src = wk; dst = wkb; off = gid - 3 * NQ - NW; }
    else if (gid < 3 * NQ + 3*NW) { src = wv; dst = wvb; off = gid - 3 * NQ - 2 * NW; }
    else                          { src = fw; dst = fwb; off = gid - 3 * NQ - 3 * NW; }
    float4 f = ((const float4*)src)[off];
    ushort4 o;
    o.x = f2bf(f.x); o.y = f2bf(f.y); o.z = f2bf(f.z); o.w = f2bf(f.w);
    ((ushort4*)dst)[off] = o;
}

// ---- sum 4 fc split-K partials + fc_b + residual -> LayerNorm -> out ----
__global__ __launch_bounds__(256) void ln_kernel(const float* __restrict__ gout,
                                                 const float* __restrict__ qin,
                                                 const float* __restrict__ fc_b,
                                                 const float* __restrict__ ln_g,
                                                 const float* __restrict__ ln_b,
                                                 float* __restrict__ out)
{
    const int row = blockIdx.x;
    const int t = threadIdx.x;
    const size_t idx = (size_t)row * Dsz + t;
    const size_t P = (size_t)NROWS * Dsz;
    const float val = gout[idx] + gout[idx + P] + gout[idx + 2 * P] + gout[idx + 3 * P]
                    + fc_b[t] + qin[idx];

    __shared__ float red[4];
    float s = val;
#pragma unroll
    for (int o = 32; o > 0; o >>= 1) s += __shfl_down(s, o, 64);
    const int lane = t & 63, w = t >> 6;
    if (lane == 0) red[w] = s;
    __syncthreads();
    const float mu = (red[0] + red[1] + red[2] + red[3]) * (1.0f / Dsz);
    __syncthreads();

    float d = val - mu;
    float s2 = d * d;
#pragma unroll
    for (int o = 32; o > 0; o >>= 1) s2 += __shfl_down(s2, o, 64);
    if (lane == 0) red[w] = s2;
    __syncthreads();
    const float var = (red[0] + red[1] + red[2] + red[3]) * (1.0f / Dsz);

    out[idx] = d * rsqrtf(var + 1e-5f) * ln_g[t] + ln_b[t];
}

extern "C" void kernel_launch(void* const* d_in, const int* in_sizes, int n_in,
                              void* d_out, int out_size, void* d_ws, size_t ws_size,
                              hipStream_t stream)
{
    const float* q    = (const float*)d_in[0];
    const int*   mask = (const int*)d_in[1];
    const float* k    = (const float*)d_in[2];
    const float* v    = (const float*)d_in[3];
    const float* w_qs = (const float*)d_in[4];
    const float* w_ks = (const float*)d_in[5];
    const float* w_vs = (const float*)d_in[6];
    const float* fc_w = (const float*)d_in[7];
    const float* fc_b = (const float*)d_in[8];
    const float* ln_g = (const float*)d_in[9];
    const float* ln_b = (const float*)d_in[10];

    float* out  = (float*)d_out;                       // [B,L,D]
    float* attn = (float*)d_out + (size_t)NROWS * Dsz; // [H*B,L,L] fp32 normalized

    // Workspace layout (ushort units)
    unsigned short* wsu = (unsigned short*)d_ws;
    unsigned short* qh     = wsu;                                  // [4096,2048]
    unsigned short* kh     = qh + (size_t)NROWS * HD;              // [4096,2048]
    unsigned short* q_bf   = kh + (size_t)NROWS * HD;              // [4096,256] x3
    unsigned short* k_bf   = q_bf + (size_t)NROWS * Dsz;
    unsigned short* v_bf   = k_bf + (size_t)NROWS * Dsz;
    unsigned short* wq_bf  = v_bf + (size_t)NROWS * Dsz;           // [2048,256] x3
    unsigned short* wk_bf  = wq_bf + (size_t)HD * Dsz;
    unsigned short* wv_bf  = wk_bf + (size_t)HD * Dsz;
    unsigned short* vt     = wv_bf + (size_t)HD * Dsz;             // [B,2048,1024]
    unsigned short* attn_e = vt + (size_t)Bsz * HD * Lsz;          // [32,1024,1024] unnormalized e
    unsigned short* attnv  = attn_e + (size_t)32 * Lsz * Lsz;      // [4096,2048]
    unsigned short* fcw_bf = attnv + (size_t)NROWS * HD;           // [256,2048]
    float*          rowsum = (float*)(fcw_bf + (size_t)Dsz * HD);  // [32768] atomic row sums
    float*          fcout  = rowsum + 32768;                       // [4,4096,256] split-K partials
    unsigned char*  maskb  = (unsigned char*)(fcout + (size_t)4 * NROWS * Dsz); // [B,L,L] bytes {0,1}

    dim3 blk(256);

    // 0) cast everything to bf16 (mask -> bytes) + zero rowsum
    cast_all<<<dim3(9248), blk, 0, stream>>>(q, k, v, w_qs, w_ks, w_vs, fc_w, mask,
                                             q_bf, k_bf, v_bf, wq_bf, wk_bf, wv_bf, fcw_bf, maskb,
                                             rowsum);

    // 1) FUSED: q/k projections (z=0,1) + vt[b] (z=2..5). 64x128 BK=64, grid 64x16x6, XCD-swizzled.
    {
        dim3 grid(NROWS / 64, HD / 128, 6);
        gemm_bt<64, 128, unsigned short, 0, 3, true, 64, 16, 6><<<grid, blk, 0, stream>>>(
            q_bf, wq_bf, qh,
            Dsz, Dsz, Dsz, HD, 2,
            0, (long long)NROWS * Dsz, 0, (long long)HD * Dsz, 0, (long long)NROWS * HD,
            1.0f, nullptr, 0, nullptr, 0, 0, nullptr,
            wv_bf, v_bf, vt);
    }

    // 2) scores + clamp/mask/exp + row-sum atomics. 64x128 BK=64, grid 16x8x32, XCD-swizzled.
    //    e stores + mask loads nontemporal.
    {
        dim3 grid(Lsz / 64, Lsz / 128, Hsz * Bsz);
        gemm_bt<64, 128, unsigned short, 1, 3, false, 16, 8, 32><<<grid, blk, 0, stream>>>(
            qh, kh, attn_e,
            Dsz, HD, HD, Lsz, Bsz,
            Dsz, (long long)Lsz * HD, Dsz, (long long)Lsz * HD,
            (long long)Bsz * Lsz * Lsz, (long long)Lsz * Lsz,
            INV_TEMP, maskb, (long long)Lsz * Lsz, nullptr, 0, 0, rowsum,
            nullptr, nullptr, nullptr);
    }

    // 3) pv: attnv = (e @ vt^T) * inv[row]; fp32 attn NT-written IN-LOOP from LDS.
    //    64x256 (full-D: A read ONCE), BK=64, K=1024, grid 16x1x32, XCD-swizzled.
    {
        dim3 grid(Lsz / 64, 1, Hsz * Bsz);
        gemm_bt<64, 256, unsigned short, 2, 2, false, 16, 1, 32><<<grid, blk, 0, stream>>>(
            attn_e, vt, attnv,
            Lsz, Lsz, Lsz, HD, Bsz,
            (long long)Bsz * Lsz * Lsz, (long long)Lsz * Lsz,
            (long long)Dsz * Lsz, (long long)HD * Lsz,
            Dsz, (long long)Lsz * HD,
            1.0f, nullptr, 0, rowsum, (long long)Bsz * Lsz, (long long)Lsz, attn,
            nullptr, nullptr, nullptr);
    }

    // 4) fc split-K x4: fcout[p] = attnv[:, p*512:+512] @ fc_w[:, p*512:+512]^T.
    //    64x128 BK=64, grid 64x2x4, XCD-swizzled. fcout stores nontemporal.
    {
        dim3 grid(NROWS / 64, Dsz / 128, 4);
        gemm_bt<64, 128, float, 0, 3, false, 64, 2, 4><<<grid, blk, 0, stream>>>(
            attnv, fcw_bf, fcout,
            512, HD, HD, Dsz, 4,
            0, 512, 0, 512, 0, (long long)NROWS * Dsz,
            1.0f, nullptr, 0, nullptr, 0, 0, nullptr,
            nullptr, nullptr, nullptr);
    }

    // 5) sum partials + bias + residual + LayerNorm
    ln_kernel<<<dim3(NROWS), blk, 0, stream>>>(fcout, q, fc_b, ln_g, ln_b, out);
}

// Round 10
// 326.196 us; speedup vs baseline: 1.1522x; 1.1522x over previous
//
#include <hip/hip_runtime.h>
#include <cstdint>
#include <math.h>

// Problem constants
#define Bsz 4
#define Lsz 1024
#define Dsz 256
#define Hsz 8
#define HD  2048          // H*D
#define NROWS (Bsz*Lsz)   // 4096
#define INV_TEMP 0.0625f  // 1/sqrt(256)

typedef __attribute__((ext_vector_type(8))) short bf16x8;
typedef __attribute__((ext_vector_type(4))) float f32x4;

__device__ inline unsigned short f2bf(float f) {
    union { float f; unsigned u; } x; x.f = f;
    unsigned r = x.u + 0x7fffu + ((x.u >> 16) & 1u);
    return (unsigned short)(r >> 16);
}
__device__ inline float bf2f(unsigned short u) {
    union { unsigned u; float f; } x; x.u = (unsigned)u << 16; return x.f;
}

#define GBL(p) ((const __attribute__((address_space(1))) unsigned int*)(p))
#define LDS(p) ((__attribute__((address_space(3))) unsigned int*)(p))

template<int N> __device__ __forceinline__ void vmw() {
    if constexpr (N == 0)       asm volatile("s_waitcnt vmcnt(0)"  ::: "memory");
    else if constexpr (N == 4)  asm volatile("s_waitcnt vmcnt(4)"  ::: "memory");
    else if constexpr (N == 6)  asm volatile("s_waitcnt vmcnt(6)"  ::: "memory");
    else if constexpr (N == 10) asm volatile("s_waitcnt vmcnt(10)" ::: "memory");
    else if constexpr (N == 14) asm volatile("s_waitcnt vmcnt(14)" ::: "memory");
    else static_assert(N == 0, "unsupported vmcnt literal");
}

// C = alpha * A @ B^T.  A [M,K] bf16 lda; Bm [N,K] bf16 ldb.
// BK=64, XOR-swizzled LDS staging + ds_read_b128 frags; counted-vmcnt dbuf pipeline.
// 4 waves as 2x2 quadrants of (TMv/2)x(TNv/2).  XCD-aware bijective wg remap (T1).
//
// Round 10: LDS ROUND-TRIP EPILOGUE. Round-9's profile showed scores at 83 us
// vs a 17-20 us roofline with MfmaUtil 8% / VALUBusy 26% / 1.3 TB/s -- the
// scattered per-element epilogue (2-byte stores in 32 B segments, scalar mask
// byte loads, 8 atomic chains/thread) is pure exposed latency at 2 wg/CU.
// Fix: after the k-loop, stage acc into LDS fp32 (padded, staging buffer is
// dead past the final barrier), then each thread handles 32 CONTIGUOUS cols of
// one row: 16 B vector mask loads, packed 16 B stores (64 B/thread coalesced),
// 4-lane shfl rowsum + ONE atomic per row. All EPI modes vectorized. NT gone.
//
// EPI: 0 = plain store; 1 = scores (clamp*mask, exp*mask, bf16, rowsum atomics);
//      2 = pv (TNv=256, gridDim.y==1): attnv scaled by inv=1/(rowsum+eps);
//          IN-LOOP: re-read A(e)-tile from LDS, normalize, write fp32 attn.
// FUSE: z<2 = q/k projection; z in [2,6) = vt[b=z-2] = w_vs @ v_b^T remapped.
template <int TMv, int TNv, typename OutT, int EPI, int MINW, bool FUSE,
          int GX, int GY, int GZ>
__global__ __launch_bounds__(256, MINW) void gemm_bt(
    const unsigned short* __restrict__ A, const unsigned short* __restrict__ Bm,
    OutT* __restrict__ C,
    int K, int lda, int ldb, int ldc, int inner,
    long long sA1, long long sA2, long long sB1, long long sB2,
    long long sC1, long long sC2, float alpha,
    const unsigned char* __restrict__ maskb, long long sM2,
    const float* __restrict__ invs, long long sI1, long long sI2,
    float* __restrict__ aux,
    const unsigned short* __restrict__ A2, const unsigned short* __restrict__ B2,
    unsigned short* __restrict__ C2)
{
    constexpr int WMv = TMv / 2, WNv = TNv / 2;
    constexpr int IT = TMv / 32, JT = TNv / 32;
    constexpr int APASS = TMv / 32, NPASS = (TMv + TNv) / 32;
    constexpr int TILE = (TMv + TNv) * 64;   // ushorts per k-tile
    constexpr int G = GX * GY * GZ;
    static_assert(G % 8 == 0, "bijective XCD swizzle needs G%8==0");
    static_assert(NPASS == 6 || NPASS == 10, "vmcnt literals assume NPASS in {6,10}");
    static_assert(EPI != 1 || TNv == 128, "EPI=1 rowsum shfl assumes 4 segs");
    // epilogue LDS reuse: TMv*(TNv+4)*4 bytes must fit in 2*TILE*2 bytes
    static_assert(TMv * (TNv + 4) * 4 <= 2 * TILE * 2, "epilogue LDS overflow");

    const int z  = blockIdx.z;   // placeholder; real z from remap below

    // ---- XCD-aware bijective remap: each XCD gets a contiguous nid chunk ----
    const int lid = blockIdx.x + GX * (blockIdx.y + GY * blockIdx.z);
    const int nid = (lid & 7) * (G >> 3) + (lid >> 3);
    int mx = nid % GX;
    const int t1g = nid / GX;
    int my = t1g % GY;
    const int zz = t1g / GY;

    if constexpr (FUSE) {
        if (zz >= 2) {
            const int idx = my * 64 + mx;
            if (idx >= 256) return;            // vt slice is 32x8 wg-tiles
            mx = idx & 31; my = idx >> 5;
            const int b = zz - 2;
            A   = A2;
            Bm  = B2 + (size_t)b * ((size_t)Lsz * Dsz);
            C   = (OutT*)(C2 + (size_t)b * ((size_t)HD * Lsz));
            ldc = Lsz;
        } else {
            A  += (size_t)zz * sA2;
            Bm += (size_t)zz * sB2;
            C  += (size_t)zz * sC2;
        }
    } else {
        const int i1 = zz / inner;
        const int i2 = zz % inner;
        A  += (size_t)i1 * sA1 + (size_t)i2 * sA2;
        Bm += (size_t)i1 * sB1 + (size_t)i2 * sB2;
        C  += (size_t)i1 * sC1 + (size_t)i2 * sC2;
        if (EPI == 1) { maskb += (size_t)i2 * sM2; aux += (size_t)zz * Lsz; }
        if (EPI == 2) { invs  += (size_t)i1 * sI1 + (size_t)i2 * sI2; aux += (size_t)zz * Lsz * Lsz; }
    }
    (void)z;

    __shared__ unsigned short S[2 * TILE];

    const int t    = threadIdx.x;
    const int lane = t & 63;
    const int w    = t >> 6;
    const int wm   = w & 1;
    const int wn   = w >> 1;
    const int m0   = mx * TMv;
    const int n0   = my * TNv;

    // staging: 32 rows per pass, 8 threads/row, 16B each; global chunk XOR-swizzled by row
    const int rA = t >> 3;
    const int ch = ((t & 7) ^ (rA & 7)) * 8;
    const unsigned short* gA = A  + (size_t)(m0 + rA) * lda + ch;
    const unsigned short* gB = Bm + (size_t)(n0 + rA) * ldb + ch;

    const int fr = lane & 15;
    const int q  = lane >> 4;

    f32x4 acc[IT][JT];
#pragma unroll
    for (int i = 0; i < IT; ++i)
#pragma unroll
        for (int j = 0; j < JT; ++j) acc[i][j] = (f32x4){0.f, 0.f, 0.f, 0.f};

    auto stage = [&](unsigned short* Sb, int k0) {
#pragma unroll
        for (int p = 0; p < NPASS; ++p) {
            const unsigned short* src = (p < APASS)
                ? (gA + (size_t)p * 32 * lda + k0)
                : (gB + (size_t)(p - APASS) * 32 * ldb + k0);
            __builtin_amdgcn_global_load_lds(GBL(src), LDS(Sb + p * 2048 + t * 8), 16, 0, 0);
        }
    };
    auto kstep = [&](const unsigned short* As) {
        const unsigned short* Bs = As + TMv * 64;
#pragma unroll
        for (int ks = 0; ks < 2; ++ks) {
            const int slot = ((ks * 4 + q) ^ (fr & 7)) * 8;  // de-swizzle
            bf16x8 a[IT], b[JT];
#pragma unroll
            for (int i = 0; i < IT; ++i)
                a[i] = *(const bf16x8*)(As + (wm * WMv + i * 16 + fr) * 64 + slot);
#pragma unroll
            for (int j = 0; j < JT; ++j)
                b[j] = *(const bf16x8*)(Bs + (wn * WNv + j * 16 + fr) * 64 + slot);
#pragma unroll
            for (int i = 0; i < IT; ++i)
#pragma unroll
                for (int j = 0; j < JT; ++j)
                    acc[i][j] = __builtin_amdgcn_mfma_f32_16x16x32_bf16(a[i], b[j], acc[i][j], 0, 0, 0);
        }
    };

    const int nk = K >> 6;

    // EPI==2: per-thread inv for the 2 in-loop attn rows (regs); drain BEFORE
    // staging so counted in-loop waits see only tile loads + attn stores.
    float ainv[EPI == 2 ? (TMv / 32) : 1];
    if constexpr (EPI == 2) {
        const int rsub = lane >> 3;
#pragma unroll
        for (int pass = 0; pass < TMv / 32; ++pass)
            ainv[pass] = 1.0f / (invs[m0 + w * (TMv / 4) + pass * 8 + rsub] + 1e-6f);
        vmw<0>();
    }

    stage(S, 0);

    for (int kt = 0; kt < nk; ++kt) {
        if (kt + 1 < nk) stage(S + ((kt + 1) & 1) * TILE, (kt + 1) << 6);

        // wait only for tile kt's loads (oldest-first retirement, m135);
        // EPI==2 adds +4 slack for the previous iteration's 4 attn stores.
        if constexpr (EPI == 2) {
            if (kt + 1 < nk) { if (kt >= 1) vmw<NPASS + 4>(); else vmw<NPASS>(); }
            else             { if (kt >= 1) vmw<4>();         else vmw<0>(); }
        } else {
            if (kt + 1 < nk) vmw<NPASS>(); else vmw<0>();
        }
        __builtin_amdgcn_s_barrier();

        kstep(S + (kt & 1) * TILE);

        if constexpr (EPI == 2) {
            // normalized fp32 attn write for this k-tile's A(e) rows, from LDS (every kt)
            const unsigned short* As = S + (kt & 1) * TILE;
            const int chunk = lane & 7;
            const int rsub  = lane >> 3;
#pragma unroll
            for (int pass = 0; pass < TMv / 32; ++pass) {
                const int row = w * (TMv / 4) + pass * 8 + rsub;
                const uint4 u = *(const uint4*)(As + row * 64 + ((chunk ^ (row & 7)) * 8));
                const float iv = ainv[pass];
                float4 lo, hi;
                lo.x = bf2f((unsigned short)(u.x & 0xffff)) * iv; lo.y = bf2f((unsigned short)(u.x >> 16)) * iv;
                lo.z = bf2f((unsigned short)(u.y & 0xffff)) * iv; lo.w = bf2f((unsigned short)(u.y >> 16)) * iv;
                hi.x = bf2f((unsigned short)(u.z & 0xffff)) * iv; hi.y = bf2f((unsigned short)(u.z >> 16)) * iv;
                hi.z = bf2f((unsigned short)(u.w & 0xffff)) * iv; hi.w = bf2f((unsigned short)(u.w >> 16)) * iv;
                float* op = aux + (size_t)(m0 + row) * Lsz + (kt << 6) + chunk * 8;
                *(float4*)op = lo;
                *(float4*)(op + 4) = hi;
            }
        }

        // readers done with buf[kt] before iter kt+1 overwrites it; do NOT drain vmcnt
        asm volatile("s_waitcnt lgkmcnt(0)" ::: "memory");
        __builtin_amdgcn_s_barrier();
    }

    // ---- epilogue: acc -> LDS fp32 (padded) -> vectorized coalesced global IO ----
    // Staging buffer is dead after the loop's final lgkmcnt(0)+barrier.
    {
        float* Lf = (float*)S;
        constexpr int LP = TNv + 4;   // pad: row stride 132/260 floats -> 2-way conflicts only (free)
#pragma unroll
        for (int i = 0; i < IT; ++i)
#pragma unroll
            for (int j = 0; j < JT; ++j) {
                const int col = wn * WNv + j * 16 + fr;
#pragma unroll
                for (int r = 0; r < 4; ++r) {
                    const int row = wm * WMv + i * 16 + q * 4 + r;
                    Lf[row * LP + col] = acc[i][j][r] * alpha;
                }
            }
        __syncthreads();

        constexpr int SEGS = TNv / 32;     // 32-col segments per row
        constexpr int RPI  = 256 / SEGS;   // rows covered per pass
#pragma unroll
        for (int it2 = 0; it2 < TMv / RPI; ++it2) {
            const int row = it2 * RPI + t / SEGS;
            const int c0  = (t % SEGS) * 32;
            const float* src = Lf + row * LP + c0;

            if constexpr (EPI == 0 && sizeof(OutT) == 4) {
                float* dst = (float*)C + (size_t)(m0 + row) * ldc + n0 + c0;
#pragma unroll
                for (int v4 = 0; v4 < 8; ++v4)
                    *(f32x4*)(dst + v4 * 4) = *(const f32x4*)(src + v4 * 4);
            } else if constexpr (EPI == 0) {
                unsigned short* dst = (unsigned short*)C + (size_t)(m0 + row) * ldc + n0 + c0;
#pragma unroll
                for (int v8 = 0; v8 < 4; ++v8) {
                    bf16x8 o;
#pragma unroll
                    for (int e = 0; e < 8; ++e) o[e] = (short)f2bf(src[v8 * 8 + e]);
                    *(bf16x8*)(dst + v8 * 8) = o;
                }
            } else if constexpr (EPI == 1) {
                unsigned short* dst = (unsigned short*)C + (size_t)(m0 + row) * ldc + n0 + c0;
                const unsigned char* mrow = maskb + (size_t)(m0 + row) * Lsz + n0 + c0;
                unsigned char mloc[32];
                *(uint4*)mloc        = *(const uint4*)mrow;
                *(uint4*)(mloc + 16) = *(const uint4*)(mrow + 16);
                float rsum = 0.f;
#pragma unroll
                for (int v8 = 0; v8 < 4; ++v8) {
                    bf16x8 o;
#pragma unroll
                    for (int e = 0; e < 8; ++e) {
                        const float m = (float)mloc[v8 * 8 + e];
                        float vv = fminf(fmaxf(src[v8 * 8 + e], -15.f), 15.f) * m;
                        vv = __expf(vv) * m;
                        const unsigned short us = f2bf(vv);
                        o[e] = (short)us;
                        rsum += bf2f(us);   // sum the ROUNDED value
                    }
                    *(bf16x8*)(dst + v8 * 8) = o;
                }
                // combine the 4 segs of this row (threads t, t^1, t^2 share the row)
                rsum += __shfl_xor(rsum, 1, 64);
                rsum += __shfl_xor(rsum, 2, 64);
                if ((t & 3) == 0) atomicAdd(&aux[m0 + row], rsum);
            } else { // EPI == 2: attnv = acc * inv[row]
                unsigned short* dst = (unsigned short*)C + (size_t)(m0 + row) * ldc + n0 + c0;
                const float iv = 1.0f / (invs[m0 + row] + 1e-6f);
#pragma unroll
                for (int v8 = 0; v8 < 4; ++v8) {
                    bf16x8 o;
#pragma unroll
                    for (int e = 0; e < 8; ++e) o[e] = (short)f2bf(src[v8 * 8 + e] * iv);
                    *(bf16x8*)(dst + v8 * 8) = o;
                }
            }
        }
    }
}

// ---- fp32->bf16 cast of all GEMM inputs + int32 mask -> BYTE {0,1} + rowsum zero ----
__global__ __launch_bounds__(256) void cast_all(
    const float* __restrict__ q, const float* __restrict__ k, const float* __restrict__ v,
    const float* __restrict__ wq, const float* __restrict__ wk, const float* __restrict__ wv,
    const float* __restrict__ fw, const int* __restrict__ mask,
    unsigned short* __restrict__ qb, unsigned short* __restrict__ kb, unsigned short* __restrict__ vb,
    unsigned short* __restrict__ wqb, unsigned short* __restrict__ wkb, unsigned short* __restrict__ wvb,
    unsigned short* __restrict__ fwb, unsigned char* __restrict__ mb,
    float* __restrict__ rs)
{
    const int gid = blockIdx.x * 256 + threadIdx.x;
    const int NQ = 262144;   // 1048576/4
    const int NW = 131072;   // 524288/4
    const int NF = 3 * NQ + 4 * NW;   // 1310720 float4 groups
    const int NM = 1048576;           // mask int4 groups
    if (gid >= NF) {
        const int off = gid - NF;
        if (off >= NM) {
            const int ri = off - NM;
            if (ri < 8192) ((float4*)rs)[ri] = (float4){0.f, 0.f, 0.f, 0.f};
            return;
        }
        const int4 mi = ((const int4*)mask)[off];
        uchar4 o;
        o.x = mi.x ? 1 : 0;
        o.y = mi.y ? 1 : 0;
        o.z = mi.z ? 1 : 0;
        o.w = mi.w ? 1 : 0;
        ((uchar4*)mb)[off] = o;
        return;
    }
    const float* src; unsigned short* dst; int off;
    if      (gid < NQ)            { src = q;  dst = qb;  off = gid; }
    else if (gid < 2 * NQ)        { src = k;  dst = kb;  off = gid - NQ; }
    else if (gid < 3 * NQ)        { src = v;  dst = vb;  off = gid - 2 * NQ; }
    else if (gid < 3 * NQ + NW)   { src = wq; dst = wqb; off = gid - 3 * NQ; }
    else if (gid < 3 * NQ + 2*NW) { src = wk; dst = wkb; off = gid - 3 * NQ - NW; }
    else if (gid < 3 * NQ + 3*NW) { src = wv; dst = wvb; off = gid - 3 * NQ - 2 * NW; }
    else                          { src = fw; dst = fwb; off = gid - 3 * NQ - 3 * NW; }
    float4 f = ((const float4*)src)[off];
    ushort4 o;
    o.x = f2bf(f.x); o.y = f2bf(f.y); o.z = f2bf(f.z); o.w = f2bf(f.w);
    ((ushort4*)dst)[off] = o;
}

// ---- sum 4 fc split-K partials + fc_b + residual -> LayerNorm -> out ----
__global__ __launch_bounds__(256) void ln_kernel(const float* __restrict__ gout,
                                                 const float* __restrict__ qin,
                                                 const float* __restrict__ fc_b,
                                                 const float* __restrict__ ln_g,
                                                 const float* __restrict__ ln_b,
                                                 float* __restrict__ out)
{
    const int row = blockIdx.x;
    const int t = threadIdx.x;
    const size_t idx = (size_t)row * Dsz + t;
    const size_t P = (size_t)NROWS * Dsz;
    const float val = gout[idx] + gout[idx + P] + gout[idx + 2 * P] + gout[idx + 3 * P]
                    + fc_b[t] + qin[idx];

    __shared__ float red[4];
    float s = val;
#pragma unroll
    for (int o = 32; o > 0; o >>= 1) s += __shfl_down(s, o, 64);
    const int lane = t & 63, w = t >> 6;
    if (lane == 0) red[w] = s;
    __syncthreads();
    const float mu = (red[0] + red[1] + red[2] + red[3]) * (1.0f / Dsz);
    __syncthreads();

    float d = val - mu;
    float s2 = d * d;
#pragma unroll
    for (int o = 32; o > 0; o >>= 1) s2 += __shfl_down(s2, o, 64);
    if (lane == 0) red[w] = s2;
    __syncthreads();
    const float var = (red[0] + red[1] + red[2] + red[3]) * (1.0f / Dsz);

    out[idx] = d * rsqrtf(var + 1e-5f) * ln_g[t] + ln_b[t];
}

extern "C" void kernel_launch(void* const* d_in, const int* in_sizes, int n_in,
                              void* d_out, int out_size, void* d_ws, size_t ws_size,
                              hipStream_t stream)
{
    const float* q    = (const float*)d_in[0];
    const int*   mask = (const int*)d_in[1];
    const float* k    = (const float*)d_in[2];
    const float* v    = (const float*)d_in[3];
    const float* w_qs = (const float*)d_in[4];
    const float* w_ks = (const float*)d_in[5];
    const float* w_vs = (const float*)d_in[6];
    const float* fc_w = (const float*)d_in[7];
    const float* fc_b = (const float*)d_in[8];
    const float* ln_g = (const float*)d_in[9];
    const float* ln_b = (const float*)d_in[10];

    float* out  = (float*)d_out;                       // [B,L,D]
    float* attn = (float*)d_out + (size_t)NROWS * Dsz; // [H*B,L,L] fp32 normalized

    // Workspace layout (ushort units)
    unsigned short* wsu = (unsigned short*)d_ws;
    unsigned short* qh     = wsu;                                  // [4096,2048]
    unsigned short* kh     = qh + (size_t)NROWS * HD;              // [4096,2048]
    unsigned short* q_bf   = kh + (size_t)NROWS * HD;              // [4096,256] x3
    unsigned short* k_bf   = q_bf + (size_t)NROWS * Dsz;
    unsigned short* v_bf   = k_bf + (size_t)NROWS * Dsz;
    unsigned short* wq_bf  = v_bf + (size_t)NROWS * Dsz;           // [2048,256] x3
    unsigned short* wk_bf  = wq_bf + (size_t)HD * Dsz;
    unsigned short* wv_bf  = wk_bf + (size_t)HD * Dsz;
    unsigned short* vt     = wv_bf + (size_t)HD * Dsz;             // [B,2048,1024]
    unsigned short* attn_e = vt + (size_t)Bsz * HD * Lsz;          // [32,1024,1024] unnormalized e
    unsigned short* attnv  = attn_e + (size_t)32 * Lsz * Lsz;      // [4096,2048]
    unsigned short* fcw_bf = attnv + (size_t)NROWS * HD;           // [256,2048]
    float*          rowsum = (float*)(fcw_bf + (size_t)Dsz * HD);  // [32768] atomic row sums
    float*          fcout  = rowsum + 32768;                       // [4,4096,256] split-K partials
    unsigned char*  maskb  = (unsigned char*)(fcout + (size_t)4 * NROWS * Dsz); // [B,L,L] bytes {0,1}

    dim3 blk(256);

    // 0) cast everything to bf16 (mask -> bytes) + zero rowsum
    cast_all<<<dim3(9248), blk, 0, stream>>>(q, k, v, w_qs, w_ks, w_vs, fc_w, mask,
                                             q_bf, k_bf, v_bf, wq_bf, wk_bf, wv_bf, fcw_bf, maskb,
                                             rowsum);

    // 1) FUSED: q/k projections (z=0,1) + vt[b] (z=2..5). 64x128 BK=64, grid 64x16x6, XCD-swizzled.
    {
        dim3 grid(NROWS / 64, HD / 128, 6);
        gemm_bt<64, 128, unsigned short, 0, 3, true, 64, 16, 6><<<grid, blk, 0, stream>>>(
            q_bf, wq_bf, qh,
            Dsz, Dsz, Dsz, HD, 2,
            0, (long long)NROWS * Dsz, 0, (long long)HD * Dsz, 0, (long long)NROWS * HD,
            1.0f, nullptr, 0, nullptr, 0, 0, nullptr,
            wv_bf, v_bf, vt);
    }

    // 2) scores + clamp/mask/exp + row-sum atomics (vectorized epilogue).
    //    64x128 BK=64, grid 16x8x32, XCD-swizzled.
    {
        dim3 grid(Lsz / 64, Lsz / 128, Hsz * Bsz);
        gemm_bt<64, 128, unsigned short, 1, 3, false, 16, 8, 32><<<grid, blk, 0, stream>>>(
            qh, kh, attn_e,
            Dsz, HD, HD, Lsz, Bsz,
            Dsz, (long long)Lsz * HD, Dsz, (long long)Lsz * HD,
            (long long)Bsz * Lsz * Lsz, (long long)Lsz * Lsz,
            INV_TEMP, maskb, (long long)Lsz * Lsz, nullptr, 0, 0, rowsum,
            nullptr, nullptr, nullptr);
    }

    // 3) pv: attnv = (e @ vt^T) * inv[row]; fp32 attn written IN-LOOP from LDS.
    //    64x256 (full-D: A read ONCE), BK=64, K=1024, grid 16x1x32, XCD-swizzled.
    {
        dim3 grid(Lsz / 64, 1, Hsz * Bsz);
        gemm_bt<64, 256, unsigned short, 2, 2, false, 16, 1, 32><<<grid, blk, 0, stream>>>(
            attn_e, vt, attnv,
            Lsz, Lsz, Lsz, HD, Bsz,
            (long long)Bsz * Lsz * Lsz, (long long)Lsz * Lsz,
            (long long)Dsz * Lsz, (long long)HD * Lsz,
            Dsz, (long long)Lsz * HD,
            1.0f, nullptr, 0, rowsum, (long long)Bsz * Lsz, (long long)Lsz, attn,
            nullptr, nullptr, nullptr);
    }

    // 4) fc split-K x4: fcout[p] = attnv[:, p*512:+512] @ fc_w[:, p*512:+512]^T.
    //    64x128 BK=64, grid 64x2x4, XCD-swizzled.
    {
        dim3 grid(NROWS / 64, Dsz / 128, 4);
        gemm_bt<64, 128, float, 0, 3, false, 64, 2, 4><<<grid, blk, 0, stream>>>(
            attnv, fcw_bf, fcout,
            512, HD, HD, Dsz, 4,
            0, 512, 0, 512, 0, (long long)NROWS * Dsz,
            1.0f, nullptr, 0, nullptr, 0, 0, nullptr,
            nullptr, nullptr, nullptr);
    }

    // 5) sum partials + bias + residual + LayerNorm
    ln_kernel<<<dim3(NROWS), blk, 0, stream>>>(fcout, q, fc_b, ln_g, ln_b, out);
}